// Round 5
// baseline (670.442 us; speedup 1.0000x reference)
//
#include <hip/hip_runtime.h>
#include <hip/hip_bf16.h>
#include <math.h>

#define NB 16384      // tokens
#define DD 2048       // hidden dim
#define NE 8          // experts
#define TM 256
#define TN 256
#define BK 64
#define NKT (DD / BK)                      // 32 K-tiles
#define NIT (NKT / 2)                      // 16 iterations (2 tiles each)
#define MT_PER_PASS (NB / TM + NE)         // 72 worst-case M-tiles per pass
#define NT_TILES (DD / TN)                 // 8
#define GEMM_GRID (MT_PER_PASS * NT_TILES) // 576 (576 % 8 == 0)

typedef float f32x4 __attribute__((ext_vector_type(4)));
typedef short bf16x8 __attribute__((ext_vector_type(8)));

__device__ __forceinline__ short f2bf(float f) {
  union { float f; unsigned u; } v; v.f = f;
  unsigned r = (v.u + 0x7FFFu + ((v.u >> 16) & 1u)) >> 16;  // RNE
  return (short)r;
}

__device__ __forceinline__ void gload16(const void* g, void* l) {
  __builtin_amdgcn_global_load_lds((const __attribute__((address_space(1))) void*)g,
                                   (__attribute__((address_space(3))) void*)l,
                                   16, 0, 0);
}

// ---- expert_w (E,D,D fp32, [d][f]) -> bf16 transposed Wt[e][f][d] ----
__global__ void conv_wT(const float* __restrict__ w, short* __restrict__ wt) {
  __shared__ float tile[64][68];
  int bid = blockIdx.x;
  int e = bid >> 10;
  int tt = bid & 1023;
  int d0 = (tt >> 5) << 6;
  int f0 = (tt & 31) << 6;
  const float* we = w + (size_t)e * DD * DD;
  int t = threadIdx.x;
  int col = (t & 15) << 2;
#pragma unroll
  for (int p = 0; p < 4; ++p) {
    int dl = (t >> 4) + p * 16;
    f32x4 v = *(const f32x4*)(we + (size_t)(d0 + dl) * DD + f0 + col);
    *(f32x4*)&tile[dl][col] = v;
  }
  __syncthreads();
  int fl = t >> 2;
  int ds = (t & 3) << 4;
  short tmp[16];
#pragma unroll
  for (int j = 0; j < 16; ++j) tmp[j] = f2bf(tile[ds + j][fl]);
  short* dst = wt + (size_t)e * DD * DD + (size_t)(f0 + fl) * DD + d0 + ds;
  *(bf16x8*)dst = *(const bf16x8*)tmp;
  *(bf16x8*)(dst + 8) = *(const bf16x8*)(tmp + 8);
}

// ---- fused: x -> bf16 conversion + gate logits (fp64) + top-2 softmax ----
__global__ void gate_conv(const float* __restrict__ x, const float* __restrict__ gw,
                          const float* __restrict__ gb, short* __restrict__ xb,
                          int* __restrict__ ridx, float* __restrict__ rw) {
  int wid = threadIdx.x >> 6;
  int lane = threadIdx.x & 63;
  int b = blockIdx.x * 4 + wid;
  const float* xr = x + (size_t)b * DD;
  short* xbr = xb + (size_t)b * DD;
  double acc[8];
#pragma unroll
  for (int e = 0; e < 8; ++e) acc[e] = 0.0;
#pragma unroll
  for (int it = 0; it < 4; ++it) {
    int d8 = (it * 64 + lane) * 8;
    f32x4 a = *(const f32x4*)(xr + d8);
    f32x4 c = *(const f32x4*)(xr + d8 + 4);
    bf16x8 o;
    o[0] = f2bf(a[0]); o[1] = f2bf(a[1]); o[2] = f2bf(a[2]); o[3] = f2bf(a[3]);
    o[4] = f2bf(c[0]); o[5] = f2bf(c[1]); o[6] = f2bf(c[2]); o[7] = f2bf(c[3]);
    *(bf16x8*)(xbr + d8) = o;
#pragma unroll
    for (int j = 0; j < 8; ++j) {
      float xv = (j < 4) ? a[j] : c[j - 4];
      double xd = (double)xv;
      f32x4 g0 = *(const f32x4*)(gw + (size_t)(d8 + j) * 8);
      f32x4 g1 = *(const f32x4*)(gw + (size_t)(d8 + j) * 8 + 4);
      acc[0] += xd * g0[0]; acc[1] += xd * g0[1];
      acc[2] += xd * g0[2]; acc[3] += xd * g0[3];
      acc[4] += xd * g1[0]; acc[5] += xd * g1[1];
      acc[6] += xd * g1[2]; acc[7] += xd * g1[3];
    }
  }
#pragma unroll
  for (int off = 32; off > 0; off >>= 1) {
#pragma unroll
    for (int e = 0; e < 8; ++e) acc[e] += __shfl_down(acc[e], off);
  }
  if (lane == 0) {
    double l[8];
#pragma unroll
    for (int e = 0; e < 8; ++e) l[e] = acc[e] + (double)gb[e];
    int i0 = 0;
#pragma unroll
    for (int e = 1; e < 8; ++e) if (l[e] > l[i0]) i0 = e;
    int i1 = (i0 == 0) ? 1 : 0;
#pragma unroll
    for (int e = 0; e < 8; ++e) if (e != i0 && l[e] > l[i1]) i1 = e;
    double z = exp(l[i1] - l[i0]);
    float w0 = (float)(1.0 / (1.0 + z));
    float w1 = (float)(z / (1.0 + z));
    ridx[2 * b] = i0; ridx[2 * b + 1] = i1;
    rw[2 * b] = w0;   rw[2 * b + 1] = w1;
  }
}

// ---- per-block histogram over 16 (k,e) buckets ----
__global__ void hist_tok(const int* __restrict__ ridx, int* __restrict__ partials) {
  __shared__ int h[16];
  int t = threadIdx.x;
  if (t < 16) h[t] = 0;
  __syncthreads();
  int t0 = blockIdx.x * 512;
  for (int i = t; i < 512; i += 256) {
    int tok = t0 + i;
    atomicAdd(&h[ridx[2 * tok]], 1);
    atomicAdd(&h[8 + ridx[2 * tok + 1]], 1);
  }
  __syncthreads();
  if (t < 16) partials[blockIdx.x * 16 + t] = h[t];
}

__global__ void scan_small(const int* __restrict__ partials, int* __restrict__ base,
                           int* __restrict__ cnts, int* __restrict__ offs) {
  __shared__ int c[16], o[16];
  int j = threadIdx.x;
  if (j < 16) {
    int s = 0;
    for (int b = 0; b < 32; ++b) s += partials[b * 16 + j];
    c[j] = s; cnts[j] = s;
  }
  __syncthreads();
  if (j < 2) {
    int a = 0;
    for (int e = 0; e < 8; ++e) { o[j * 8 + e] = a; a += c[j * 8 + e]; }
  }
  __syncthreads();
  if (j < 16) {
    int r = o[j];
    offs[j] = o[j];
    for (int b = 0; b < 32; ++b) { base[b * 16 + j] = r; r += partials[b * 16 + j]; }
  }
}

__global__ void scatter_tok(const int* __restrict__ ridx, const float* __restrict__ rw,
                            const int* __restrict__ base,
                            int* __restrict__ lists0, float* __restrict__ elw0,
                            int* __restrict__ lists1, float* __restrict__ elw1) {
  __shared__ int h[16];
  int t = threadIdx.x;
  if (t < 16) h[t] = 0;
  __syncthreads();
  int t0 = blockIdx.x * 512;
  const int* bb = base + blockIdx.x * 16;
  for (int i = t; i < 512; i += 256) {
    int tok = t0 + i;
    int e0 = ridx[2 * tok], e1 = ridx[2 * tok + 1];
    int r0 = atomicAdd(&h[e0], 1);
    int r1 = atomicAdd(&h[8 + e1], 1);
    int p0 = bb[e0] + r0;
    int p1 = bb[8 + e1] + r1;
    lists0[p0] = tok; elw0[p0] = rw[2 * tok];
    lists1[p1] = tok; elw1[p1] = rw[2 * tok + 1];
  }
}

// ========== 256x256 8-phase grouped GEMM, >=3-phase issue-to-wait ==========
#define VMCNT4 asm volatile("s_waitcnt vmcnt(4)" ::: "memory")
#define VMCNT0 asm volatile("s_waitcnt vmcnt(0)" ::: "memory")
#define NOWAIT ((void)0)
#define NOSTAGE ((void)0)
#define NORD ((void)0)

// stage-half h covers rows h*128..h*128+127 (2 gload16 instructions)
#define STAGE_AH(buf, h, kt) {                                                  \
  gload16(aptr[h][0] + (size_t)(kt) * 64, &As[(buf)*16384 + (h)*8192 + tid*8]); \
  gload16(aptr[h][1] + (size_t)(kt) * 64, &As[(buf)*16384 + (h)*8192 + 4096 + tid*8]); }

#define STAGE_BH(buf, h, kt) {                                                  \
  gload16(bptr[h][0] + (size_t)(kt) * 64, &Bs[(buf)*16384 + (h)*8192 + tid*8]); \
  gload16(bptr[h][1] + (size_t)(kt) * 64, &Bs[(buf)*16384 + (h)*8192 + 4096 + tid*8]); }

#define READ_A(buf, mh)                                                         \
  _Pragma("unroll") for (int i4 = 0; i4 < 4; ++i4) {                            \
    af[i4][0] = *(const bf16x8*)&As[(buf)*16384 + arow + ((mh)*64 + i4*16)*64 + csw0]; \
    af[i4][1] = *(const bf16x8*)&As[(buf)*16384 + arow + ((mh)*64 + i4*16)*64 + csw1]; }

#define READ_B(buf, nh, dst)                                                    \
  _Pragma("unroll") for (int j2 = 0; j2 < 2; ++j2) {                            \
    dst[j2][0] = *(const bf16x8*)&Bs[(buf)*16384 + brow + ((nh)*32 + j2*16)*64 + csw0]; \
    dst[j2][1] = *(const bf16x8*)&Bs[(buf)*16384 + brow + ((nh)*32 + j2*16)*64 + csw1]; }

#define MFMA16(mh, nh, B)                                                       \
  _Pragma("unroll") for (int i4 = 0; i4 < 4; ++i4)                              \
  _Pragma("unroll") for (int j2 = 0; j2 < 2; ++j2) {                            \
    acc[(mh)*4+i4][(nh)*2+j2] = __builtin_amdgcn_mfma_f32_16x16x32_bf16(        \
        af[i4][0], B[j2][0], acc[(mh)*4+i4][(nh)*2+j2], 0, 0, 0);               \
    acc[(mh)*4+i4][(nh)*2+j2] = __builtin_amdgcn_mfma_f32_16x16x32_bf16(        \
        af[i4][1], B[j2][1], acc[(mh)*4+i4][(nh)*2+j2], 0, 0, 0); }

#define PHASE(RD, STG, WAIT, mh, nh, B) {                                       \
  RD;                                                                           \
  STG;                                                                          \
  WAIT;                                                                         \
  __builtin_amdgcn_s_barrier();                                                 \
  asm volatile("s_waitcnt lgkmcnt(0)" ::: "memory");                            \
  __builtin_amdgcn_sched_barrier(0);                                            \
  __builtin_amdgcn_s_setprio(1);                                                \
  MFMA16(mh, nh, B);                                                            \
  __builtin_amdgcn_s_setprio(0);                                                \
  __builtin_amdgcn_s_barrier(); }

template <int ADD>
__global__ __launch_bounds__(512, 2)
void moe_gemm(const short* __restrict__ xb, const short* __restrict__ wt,
              const float* __restrict__ eb, const int* __restrict__ cnts,
              const int* __restrict__ offs, const int* __restrict__ lists,
              const float* __restrict__ elw, float* __restrict__ out) {
  __shared__ short As[2 * 16384];   // [2 dbuf][256 rows][64 k] bf16, XOR-swizzled
  __shared__ short Bs[2 * 16384];

  // XCD-chunked swizzle: XCD k owns nt column k
  int nt = blockIdx.x & 7;
  int mt = blockIdx.x >> 3;

  int e = 0, cnt = 0;
  for (; e < NE; ++e) {
    cnt = cnts[e];
    int te = (cnt + TM - 1) >> 8;
    if (mt < te) break;
    mt -= te;
  }
  if (e >= NE) return;

  int m0 = mt * TM;
  int n0 = nt * TN;
  int off_e = offs[e];
  int tid = threadIdx.x;
  int lane = tid & 63, wid = tid >> 6;
  int wr = wid >> 2, wc = wid & 3;        // 2 x 4 waves; wave out = 128 x 64

  // staging: linear LDS dest (tid*16B), inverse-swizzled source column
  int trow = tid >> 3;                    // 0..63
  int scol = ((tid & 7) ^ (trow & 7)) << 3;
  const short* aptr[2][2];
  const short* bptr[2][2];
#pragma unroll
  for (int h = 0; h < 2; ++h)
#pragma unroll
    for (int l = 0; l < 2; ++l) {
      int r = h * 128 + l * 64 + trow;
      int gr = m0 + r;
      int tok = lists[off_e + ((gr < cnt) ? gr : (cnt - 1))];
      aptr[h][l] = xb + (size_t)tok * DD + scol;
      bptr[h][l] = wt + ((size_t)e * DD + (size_t)(n0 + r)) * DD + scol;
    }

  // fragment read addressing (swizzle XOR folds to lane&7)
  int lane15 = lane & 15;
  int csw0 = (((lane >> 4)    ) ^ (lane & 7)) << 3;
  int csw1 = (((lane >> 4) + 4) ^ (lane & 7)) << 3;
  int arow = (wr * 128 + lane15) * 64;
  int brow = (wc * 64  + lane15) * 64;

  f32x4 acc[8][4];
#pragma unroll
  for (int i = 0; i < 8; ++i)
#pragma unroll
    for (int j = 0; j < 4; ++j) acc[i][j] = (f32x4){0.f, 0.f, 0.f, 0.f};

  bf16x8 af[4][2], bf0[2][2], bf1[2][2];

  // prologue: tile0 full + tile1 h0 halves (12 gload instrs); wait tile0 (leave 4)
  STAGE_AH(0, 0, 0); STAGE_AH(0, 1, 0); STAGE_BH(0, 0, 0); STAGE_BH(0, 1, 0);
  STAGE_AH(1, 0, 1); STAGE_BH(1, 0, 1);
  VMCNT4;
  __builtin_amdgcn_s_barrier();

  // steady state: i = 0..NIT-2 (t2k,t3k always < NKT)
  for (int i = 0; i < NIT - 1; ++i) {
    int t1k = 2 * i + 1, t2k = 2 * i + 2, t3k = 2 * i + 3;
    // tile 2i from buf0
    PHASE({ READ_A(0, 0); READ_B(0, 0, bf0); },
          { STAGE_AH(1, 1, t1k); STAGE_BH(1, 1, t1k); }, NOWAIT, 0, 0, bf0);
    PHASE({ READ_B(0, 1, bf1); }, NOSTAGE, NOWAIT, 0, 1, bf1);
    PHASE({ READ_A(0, 1); },      NOSTAGE, NOWAIT, 1, 1, bf1);
    PHASE(NORD, { STAGE_AH(0, 0, t2k); STAGE_BH(0, 0, t2k); }, VMCNT4, 1, 0, bf0);
    // tile 2i+1 from buf1
    PHASE({ READ_A(1, 0); READ_B(1, 0, bf0); },
          { STAGE_AH(0, 1, t2k); STAGE_BH(0, 1, t2k); }, NOWAIT, 0, 0, bf0);
    PHASE({ READ_B(1, 1, bf1); }, NOSTAGE, NOWAIT, 0, 1, bf1);
    PHASE({ READ_A(1, 1); },      NOSTAGE, NOWAIT, 1, 1, bf1);
    PHASE(NORD, { STAGE_AH(1, 0, t3k); STAGE_BH(1, 0, t3k); }, VMCNT4, 1, 0, bf0);
  }
  // peeled last iteration: tiles NKT-2 (buf0), NKT-1 (buf1); no new stages
  {
    PHASE({ READ_A(0, 0); READ_B(0, 0, bf0); },
          { STAGE_AH(1, 1, NKT - 1); STAGE_BH(1, 1, NKT - 1); }, NOWAIT, 0, 0, bf0);
    PHASE({ READ_B(0, 1, bf1); }, NOSTAGE, NOWAIT, 0, 1, bf1);
    PHASE({ READ_A(0, 1); },      NOSTAGE, NOWAIT, 1, 1, bf1);
    PHASE(NORD, NOSTAGE, VMCNT0, 1, 0, bf0);
    PHASE({ READ_A(1, 0); READ_B(1, 0, bf0); }, NOSTAGE, NOWAIT, 0, 0, bf0);
    PHASE({ READ_B(1, 1, bf1); }, NOSTAGE, NOWAIT, 0, 1, bf1);
    PHASE({ READ_A(1, 1); },      NOSTAGE, NOWAIT, 1, 1, bf1);
    PHASE(NORD, NOSTAGE, NOWAIT, 1, 0, bf0);
  }

  // epilogue: bias + relu + gate-weight; nontemporal store / load-add-store
  float ebv[4];
#pragma unroll
  for (int j4 = 0; j4 < 4; ++j4)
    ebv[j4] = eb[e * DD + n0 + wc * 64 + j4 * 16 + lane15];
  int r0 = (lane >> 4) << 2;
#pragma unroll
  for (int i8 = 0; i8 < 8; ++i8) {
    int mloc = wr * 128 + i8 * 16 + r0;
#pragma unroll
    for (int r = 0; r < 4; ++r) {
      int gr = m0 + mloc + r;
      if (gr >= cnt) continue;
      int tok = lists[off_e + gr];
      float wgt = elw[off_e + gr];
      float* orow = out + (size_t)tok * DD;
#pragma unroll
      for (int j4 = 0; j4 < 4; ++j4) {
        int n = n0 + wc * 64 + j4 * 16 + lane15;
        float v = acc[i8][j4][r] + ebv[j4];
        v = fmaxf(v, 0.f) * wgt;
        if (ADD) v += __builtin_nontemporal_load(&orow[n]);
        __builtin_nontemporal_store(v, &orow[n]);
      }
    }
  }
}

extern "C" void kernel_launch(void* const* d_in, const int* in_sizes, int n_in,
                              void* d_out, int out_size, void* d_ws, size_t ws_size,
                              hipStream_t stream) {
  const float* x   = (const float*)d_in[0];
  const float* ewt = (const float*)d_in[1];
  const float* eb  = (const float*)d_in[2];
  const float* gw  = (const float*)d_in[3];
  const float* gb  = (const float*)d_in[4];
  float* out = (float*)d_out;

  char* ws = (char*)d_ws;
  short* xb      = (short*)(ws);                     // 67108864 B
  short* wt      = (short*)(ws + 67108864);          // 67108864 B
  int*   ridx    = (int*)  (ws + 134217728);         // 131072 B
  float* rw      = (float*)(ws + 134348800);         // 131072 B
  int*   lists0  = (int*)  (ws + 134479872);         // 65536 B
  float* elw0    = (float*)(ws + 134545408);         // 65536 B
  int*   lists1  = (int*)  (ws + 134610944);         // 65536 B
  float* elw1    = (float*)(ws + 134676480);         // 65536 B
  int*   partials= (int*)  (ws + 134742016);         // 2048 B
  int*   base    = (int*)  (ws + 134744064);         // 2048 B
  int*   cnts    = (int*)  (ws + 134746112);         // 64 B
  int*   offs    = (int*)  (ws + 134746176);         // 64 B

  conv_wT<<<NE * 32 * 32, 256, 0, stream>>>(ewt, wt);
  gate_conv<<<NB / 4, 256, 0, stream>>>(x, gw, gb, xb, ridx, rw);
  hist_tok<<<32, 256, 0, stream>>>(ridx, partials);
  scan_small<<<1, 64, 0, stream>>>(partials, base, cnts, offs);
  scatter_tok<<<32, 256, 0, stream>>>(ridx, rw, base, lists0, elw0, lists1, elw1);
  moe_gemm<0><<<GEMM_GRID, 512, 0, stream>>>(xb, wt, eb, cnts,     offs,     lists0, elw0, out);
  moe_gemm<1><<<GEMM_GRID, 512, 0, stream>>>(xb, wt, eb, cnts + 8, offs + 8, lists1, elw1, out);
}

// Round 6
// 618.682 us; speedup vs baseline: 1.0837x; 1.0837x over previous
//
#include <hip/hip_runtime.h>
#include <hip/hip_bf16.h>
#include <math.h>

#define NB 16384      // tokens
#define DD 2048       // hidden dim
#define NE 8          // experts
#define TM 128
#define TN 128
#define BK 64
#define NKT (DD / BK)                      // 32 K-tiles
#define MT_PER_PASS (NB / TM + NE)         // 136 worst-case M-tiles per pass
#define NT_TILES (DD / TN)                 // 16
#define GEMM_GRID (MT_PER_PASS * NT_TILES) // 2176 (2176 % 8 == 0)
#define BPX (GEMM_GRID / 8)                // 272

typedef float f32x4 __attribute__((ext_vector_type(4)));
typedef short bf16x8 __attribute__((ext_vector_type(8)));

__device__ __forceinline__ short f2bf(float f) {
  union { float f; unsigned u; } v; v.f = f;
  unsigned r = (v.u + 0x7FFFu + ((v.u >> 16) & 1u)) >> 16;  // RNE
  return (short)r;
}

__device__ __forceinline__ void gload16(const void* g, void* l) {
  __builtin_amdgcn_global_load_lds((const __attribute__((address_space(1))) void*)g,
                                   (__attribute__((address_space(3))) void*)l,
                                   16, 0, 0);
}

// ---- expert_w (E,D,D fp32, [d][f]) -> bf16 transposed Wt[e][f][d] ----
__global__ void conv_wT(const float* __restrict__ w, short* __restrict__ wt) {
  __shared__ float tile[64][68];
  int bid = blockIdx.x;
  int e = bid >> 10;
  int tt = bid & 1023;
  int d0 = (tt >> 5) << 6;
  int f0 = (tt & 31) << 6;
  const float* we = w + (size_t)e * DD * DD;
  int t = threadIdx.x;
  int col = (t & 15) << 2;
#pragma unroll
  for (int p = 0; p < 4; ++p) {
    int dl = (t >> 4) + p * 16;
    f32x4 v = *(const f32x4*)(we + (size_t)(d0 + dl) * DD + f0 + col);
    *(f32x4*)&tile[dl][col] = v;
  }
  __syncthreads();
  int fl = t >> 2;
  int ds = (t & 3) << 4;
  short tmp[16];
#pragma unroll
  for (int j = 0; j < 16; ++j) tmp[j] = f2bf(tile[ds + j][fl]);
  short* dst = wt + (size_t)e * DD * DD + (size_t)(f0 + fl) * DD + d0 + ds;
  *(bf16x8*)dst = *(const bf16x8*)tmp;
  *(bf16x8*)(dst + 8) = *(const bf16x8*)(tmp + 8);
}

// ---- fused: x -> bf16 conversion + gate logits (fp64) + top-2 softmax ----
__global__ void gate_conv(const float* __restrict__ x, const float* __restrict__ gw,
                          const float* __restrict__ gb, short* __restrict__ xb,
                          int* __restrict__ ridx, float* __restrict__ rw) {
  int wid = threadIdx.x >> 6;
  int lane = threadIdx.x & 63;
  int b = blockIdx.x * 4 + wid;
  const float* xr = x + (size_t)b * DD;
  short* xbr = xb + (size_t)b * DD;
  double acc[8];
#pragma unroll
  for (int e = 0; e < 8; ++e) acc[e] = 0.0;
#pragma unroll
  for (int it = 0; it < 4; ++it) {
    int d8 = (it * 64 + lane) * 8;
    f32x4 a = *(const f32x4*)(xr + d8);
    f32x4 c = *(const f32x4*)(xr + d8 + 4);
    bf16x8 o;
    o[0] = f2bf(a[0]); o[1] = f2bf(a[1]); o[2] = f2bf(a[2]); o[3] = f2bf(a[3]);
    o[4] = f2bf(c[0]); o[5] = f2bf(c[1]); o[6] = f2bf(c[2]); o[7] = f2bf(c[3]);
    *(bf16x8*)(xbr + d8) = o;
#pragma unroll
    for (int j = 0; j < 8; ++j) {
      float xv = (j < 4) ? a[j] : c[j - 4];
      double xd = (double)xv;
      f32x4 g0 = *(const f32x4*)(gw + (size_t)(d8 + j) * 8);
      f32x4 g1 = *(const f32x4*)(gw + (size_t)(d8 + j) * 8 + 4);
      acc[0] += xd * g0[0]; acc[1] += xd * g0[1];
      acc[2] += xd * g0[2]; acc[3] += xd * g0[3];
      acc[4] += xd * g1[0]; acc[5] += xd * g1[1];
      acc[6] += xd * g1[2]; acc[7] += xd * g1[3];
    }
  }
#pragma unroll
  for (int off = 32; off > 0; off >>= 1) {
#pragma unroll
    for (int e = 0; e < 8; ++e) acc[e] += __shfl_down(acc[e], off);
  }
  if (lane == 0) {
    double l[8];
#pragma unroll
    for (int e = 0; e < 8; ++e) l[e] = acc[e] + (double)gb[e];
    int i0 = 0;
#pragma unroll
    for (int e = 1; e < 8; ++e) if (l[e] > l[i0]) i0 = e;
    int i1 = (i0 == 0) ? 1 : 0;
#pragma unroll
    for (int e = 0; e < 8; ++e) if (e != i0 && l[e] > l[i1]) i1 = e;
    double z = exp(l[i1] - l[i0]);
    float w0 = (float)(1.0 / (1.0 + z));
    float w1 = (float)(z / (1.0 + z));
    ridx[2 * b] = i0; ridx[2 * b + 1] = i1;
    rw[2 * b] = w0;   rw[2 * b + 1] = w1;
  }
}

// ---- per-block histogram over 16 (k,e) buckets ----
__global__ void hist_tok(const int* __restrict__ ridx, int* __restrict__ partials) {
  __shared__ int h[16];
  int t = threadIdx.x;
  if (t < 16) h[t] = 0;
  __syncthreads();
  int t0 = blockIdx.x * 512;
  for (int i = t; i < 512; i += 256) {
    int tok = t0 + i;
    atomicAdd(&h[ridx[2 * tok]], 1);
    atomicAdd(&h[8 + ridx[2 * tok + 1]], 1);
  }
  __syncthreads();
  if (t < 16) partials[blockIdx.x * 16 + t] = h[t];
}

__global__ void scan_small(const int* __restrict__ partials, int* __restrict__ base,
                           int* __restrict__ cnts, int* __restrict__ offs) {
  __shared__ int c[16], o[16];
  int j = threadIdx.x;
  if (j < 16) {
    int s = 0;
    for (int b = 0; b < 32; ++b) s += partials[b * 16 + j];
    c[j] = s; cnts[j] = s;
  }
  __syncthreads();
  if (j < 2) {
    int a = 0;
    for (int e = 0; e < 8; ++e) { o[j * 8 + e] = a; a += c[j * 8 + e]; }
  }
  __syncthreads();
  if (j < 16) {
    int r = o[j];
    offs[j] = o[j];
    for (int b = 0; b < 32; ++b) { base[b * 16 + j] = r; r += partials[b * 16 + j]; }
  }
}

__global__ void scatter_tok(const int* __restrict__ ridx, const float* __restrict__ rw,
                            const int* __restrict__ base,
                            int* __restrict__ lists0, float* __restrict__ elw0,
                            int* __restrict__ lists1, float* __restrict__ elw1) {
  __shared__ int h[16];
  int t = threadIdx.x;
  if (t < 16) h[t] = 0;
  __syncthreads();
  int t0 = blockIdx.x * 512;
  const int* bb = base + blockIdx.x * 16;
  for (int i = t; i < 512; i += 256) {
    int tok = t0 + i;
    int e0 = ridx[2 * tok], e1 = ridx[2 * tok + 1];
    int r0 = atomicAdd(&h[e0], 1);
    int r1 = atomicAdd(&h[8 + e1], 1);
    int p0 = bb[e0] + r0;
    int p1 = bb[8 + e1] + r1;
    lists0[p0] = tok; elw0[p0] = rw[2 * tok];
    lists1[p1] = tok; elw1[p1] = rw[2 * tok + 1];
  }
}

// ===== 128x128 single-buffer 2-phase grouped GEMM, register-dieted =====
// Target: unified VGPR+AGPR <= 128 -> 16 waves/CU -> 4 independent blocks/CU
template <int ADD>
__global__ __launch_bounds__(256, 4)
void moe_gemm(const short* __restrict__ xb, const short* __restrict__ wt,
              const float* __restrict__ eb, const int* __restrict__ cnts,
              const int* __restrict__ offs, const int* __restrict__ lists,
              const float* __restrict__ elw, float* __restrict__ out) {
  __shared__ short As[TM * BK];   // 16 KiB, XOR-swizzled storage
  __shared__ short Bs[TN * BK];   // 16 KiB

  int bid = blockIdx.x;
  int swz = (bid & 7) * BPX + (bid >> 3);
  int mt = swz % MT_PER_PASS;
  int nt = swz / MT_PER_PASS;

  int e = 0, cnt = 0;
  for (; e < NE; ++e) {
    cnt = cnts[e];
    int te = (cnt + TM - 1) >> 7;
    if (mt < te) break;
    mt -= te;
  }
  if (e >= NE) return;

  int m0 = mt * TM;
  int n0 = nt * TN;
  int off_e = offs[e];
  int tid = threadIdx.x;
  int lane = tid & 63, wid = tid >> 6;
  int wr = wid >> 1, wc = wid & 1;      // 2x2 waves; wave out = 64x64

  // staging coords: linear LDS dest = l*4096B + tid*16B; inverse-swz source col
  int trow = tid >> 3;                  // 0..31
  int scol = ((tid & 7) ^ (trow & 7)) << 3;
  // 4 token indices (A gather) kept as ints; addresses recomputed per K-step
  int tok[4];
#pragma unroll
  for (int l = 0; l < 4; ++l) {
    int gr = m0 + l * 32 + trow;
    tok[l] = lists[off_e + ((gr < cnt) ? gr : (cnt - 1))];
  }
  const short* bbase = wt + ((size_t)e * DD + (size_t)(n0 + trow)) * DD + scol;

  // fragment read addressing (swizzle XOR folds to lane&7)
  int lane15 = lane & 15;
  int csw0 = (((lane >> 4)    ) ^ (lane & 7)) << 3;
  int csw1 = (((lane >> 4) + 4) ^ (lane & 7)) << 3;
  int arow = (wr * 64 + lane15) * 64;
  int brow = (wc * 64 + lane15) * 64;

  f32x4 acc[4][4];
#pragma unroll
  for (int i = 0; i < 4; ++i)
#pragma unroll
    for (int j = 0; j < 4; ++j) acc[i][j] = (f32x4){0.f, 0.f, 0.f, 0.f};

#pragma unroll 1
  for (int kt = 0; kt < NKT; ++kt) {
    int ko = kt * BK + scol;   // recomputed; low reg footprint
#pragma unroll
    for (int l = 0; l < 4; ++l) {
      gload16(xb + ((size_t)tok[l] << 11) + ko, &As[l * 2048 + tid * 8]);
      gload16(bbase + (size_t)(l * 32) * DD + kt * BK, &Bs[l * 2048 + tid * 8]);
    }
    __syncthreads();
    bf16x8 bfr[4][2];
#pragma unroll
    for (int j = 0; j < 4; ++j) {
      int br = brow + j * 16 * 64;
      bfr[j][0] = *(const bf16x8*)&Bs[br + csw0];
      bfr[j][1] = *(const bf16x8*)&Bs[br + csw1];
    }
#pragma unroll
    for (int i = 0; i < 4; ++i) {
      int ar = arow + i * 16 * 64;
      bf16x8 a0 = *(const bf16x8*)&As[ar + csw0];
      bf16x8 a1 = *(const bf16x8*)&As[ar + csw1];
#pragma unroll
      for (int j = 0; j < 4; ++j) {
        acc[i][j] = __builtin_amdgcn_mfma_f32_16x16x32_bf16(a0, bfr[j][0], acc[i][j], 0, 0, 0);
        acc[i][j] = __builtin_amdgcn_mfma_f32_16x16x32_bf16(a1, bfr[j][1], acc[i][j], 0, 0, 0);
      }
    }
    __syncthreads();
  }

  // epilogue: bias + relu + gate-weight; nontemporal store / load-add-store
  int r0 = (lane >> 4) << 2;
#pragma unroll
  for (int i = 0; i < 4; ++i) {
    int mloc = wr * 64 + i * 16 + r0;
#pragma unroll
    for (int r = 0; r < 4; ++r) {
      int gr = m0 + mloc + r;
      if (gr >= cnt) continue;
      int tokr = lists[off_e + gr];
      float wgt = elw[off_e + gr];
      float* orow = out + (size_t)tokr * DD;
#pragma unroll
      for (int j = 0; j < 4; ++j) {
        int n = n0 + wc * 64 + j * 16 + lane15;
        float v = acc[i][j][r] + eb[e * DD + n];
        v = fmaxf(v, 0.f) * wgt;
        if (ADD) v += __builtin_nontemporal_load(&orow[n]);
        __builtin_nontemporal_store(v, &orow[n]);
      }
    }
  }
}

extern "C" void kernel_launch(void* const* d_in, const int* in_sizes, int n_in,
                              void* d_out, int out_size, void* d_ws, size_t ws_size,
                              hipStream_t stream) {
  const float* x   = (const float*)d_in[0];
  const float* ewt = (const float*)d_in[1];
  const float* eb  = (const float*)d_in[2];
  const float* gw  = (const float*)d_in[3];
  const float* gb  = (const float*)d_in[4];
  float* out = (float*)d_out;

  char* ws = (char*)d_ws;
  short* xb      = (short*)(ws);                     // 67108864 B
  short* wt      = (short*)(ws + 67108864);          // 67108864 B
  int*   ridx    = (int*)  (ws + 134217728);         // 131072 B
  float* rw      = (float*)(ws + 134348800);         // 131072 B
  int*   lists0  = (int*)  (ws + 134479872);         // 65536 B
  float* elw0    = (float*)(ws + 134545408);         // 65536 B
  int*   lists1  = (int*)  (ws + 134610944);         // 65536 B
  float* elw1    = (float*)(ws + 134676480);         // 65536 B
  int*   partials= (int*)  (ws + 134742016);         // 2048 B
  int*   base    = (int*)  (ws + 134744064);         // 2048 B
  int*   cnts    = (int*)  (ws + 134746112);         // 64 B
  int*   offs    = (int*)  (ws + 134746176);         // 64 B

  conv_wT<<<NE * 32 * 32, 256, 0, stream>>>(ewt, wt);
  gate_conv<<<NB / 4, 256, 0, stream>>>(x, gw, gb, xb, ridx, rw);
  hist_tok<<<32, 256, 0, stream>>>(ridx, partials);
  scan_small<<<1, 64, 0, stream>>>(partials, base, cnts, offs);
  scatter_tok<<<32, 256, 0, stream>>>(ridx, rw, base, lists0, elw0, lists1, elw1);
  moe_gemm<0><<<GEMM_GRID, 256, 0, stream>>>(xb, wt, eb, cnts,     offs,     lists0, elw0, out);
  moe_gemm<1><<<GEMM_GRID, 256, 0, stream>>>(xb, wt, eb, cnts + 8, offs + 8, lists1, elw1, out);
}